// Round 14
// baseline (992.066 us; speedup 1.0000x reference)
//
#include <hip/hip_runtime.h>
#include <math.h>

typedef unsigned short u16;
typedef __attribute__((ext_vector_type(8))) short bf16x8;     // 8 bf16 = 4 VGPRs (MFMA A/B frag)
typedef __attribute__((ext_vector_type(8))) unsigned short u16x8;
typedef __attribute__((ext_vector_type(4))) float f32x4;      // MFMA C/D frag

#define MFMA(a, b, c) __builtin_amdgcn_mfma_f32_16x16x32_bf16((a), (b), (c), 0, 0, 0)

// async global->LDS, 16B per lane; LDS dest = wave-uniform base + lane*16,
// global source = per-lane VGPR address (gather OK)
#define GLOAD_LDS16(g, l)                                                     \
  __builtin_amdgcn_global_load_lds(                                           \
      (const __attribute__((address_space(1))) void*)(g),                     \
      (__attribute__((address_space(3))) void*)(l), 16, 0, 0)

// DRAIN_VMEM: all in-flight global_load_lds landed in LDS (explicit, before barrier)
#define DRAIN_VMEM() asm volatile("s_waitcnt vmcnt(0)" ::: "memory")
// FENCE_LDS: order same-wave ds_write -> ds_read handoff (Pt) explicitly.
#define FENCE_LDS()                                                            \
  do {                                                                         \
    asm volatile("s_waitcnt lgkmcnt(0)" ::: "memory");                         \
    __builtin_amdgcn_sched_barrier(0);                                         \
  } while (0)

__device__ __forceinline__ float bf2f(u16 u) {
  union { unsigned int i; float f; } x; x.i = ((unsigned int)u) << 16; return x.f;
}
__device__ __forceinline__ u16 f2bf(float f) {
  union { float f; unsigned int i; } x; x.f = f;
  unsigned int r = x.i + 0x7FFFu + ((x.i >> 16) & 1u);   // round-to-nearest-even
  return (u16)(r >> 16);
}

// ---------------------------------------------------------------------------
// Dtype probes, one launch: flag[i]=1 bf16, 0 fp32.
// ---------------------------------------------------------------------------
__global__ __launch_bounds__(256) void probe_all(const u16* p0, const u16* p1,
                                                 const u16* p2, const u16* p3,
                                                 const u16* p4, const u16* p5,
                                                 int* __restrict__ flags) {
  const u16* ps[6] = {p0, p1, p2, p3, p4, p5};
  const u16* p = ps[blockIdx.x];
  __shared__ int cnt;
  if (threadIdx.x == 0) cnt = 0;
  __syncthreads();
  const u16 u = p[threadIdx.x * 2];
  const int e = (u >> 7) & 0xFF;
  atomicAdd(&cnt, (e >= 110 && e <= 135) ? 1 : 0);
  __syncthreads();
  if (threadIdx.x == 0) flags[blockIdx.x] = (cnt > 128) ? 1 : 0;
}

// ---------------------------------------------------------------------------
// prep_all: merged bf16 canonicalization of x + 4 weights, plus mexp build.
// blocks [0, 12288): converts (x: 4096 blocks, then Wq/Wk/Wv/Wo: 2048 each,
// outputs contiguous from xc). blocks [12288, 12304): mexp.
// ---------------------------------------------------------------------------
__global__ __launch_bounds__(256) void prep_all(const void* __restrict__ x_in,
                                                const void* __restrict__ wq_in,
                                                const void* __restrict__ wk_in,
                                                const void* __restrict__ wv_in,
                                                const void* __restrict__ wo_in,
                                                const void* __restrict__ mask_in,
                                                u16* __restrict__ xc,
                                                float* __restrict__ mexp,
                                                const int* __restrict__ flags) {
  const int blk = blockIdx.x;
  if (blk < 12288) {
    const int i = blk * 256 + threadIdx.x;
    const void* in; u16* out; int fi, off;
    if (i < (1 << 20)) {                 // x: NX/8 = 2^20 vec8 elems
      in = x_in; out = xc; fi = 0; off = i;
    } else {
      const int k = i - (1 << 20);
      const int seg = k >> 19;           // each W: NW/8 = 2^19 vec8 elems
      off = k & ((1 << 19) - 1);
      in = (seg == 0) ? wq_in : (seg == 1) ? wk_in : (seg == 2) ? wv_in : wo_in;
      out = xc + ((size_t)1 << 23) + ((size_t)seg << 22);  // Wqc..Woc contiguous
      fi = 2 + seg;
    }
    if (flags[fi]) {
      ((u16x8*)out)[off] = ((const u16x8*)in)[off];
    } else {
      const float* f = (const float*)in + (size_t)off * 8;
      u16x8 r;
#pragma unroll
      for (int j = 0; j < 8; ++j) r[j] = f2bf(f[j]);
      ((u16x8*)out)[off] = r;
    }
  } else {
    const int i = (blk - 12288) * 256 + threadIdx.x;   // 0..4095
    const float m = flags[1] ? bf2f(((const u16*)mask_in)[i]) : ((const float*)mask_in)[i];
    mexp[i] = (1.0f - m) * -1e9f;
  }
}

// ---------------------------------------------------------------------------
// GEMM: C[M,N] = A[M,K] @ B[N,K]^T, bf16 in. 128x128 tile, BK=64,
// double-buffered global_load_lds staging, single barrier per K-iter.
// XOR-swizzled unpadded LDS: chunk c of row r stored at c^(r&7).
// XCD-aware block swizzle (T1): bijective since nwg%8==0 for both grids.
// mode 2: fp32 out [M,2048]
// mode 3: QKV fused, N=6144; band 0/1 -> bf16 [B,H,S,D] (Q/K) WITH FUSED
//         ROPE (pair (dd,dd+64) exchanged via LDS across adjacent waves,
//         1/sqrt(128) folded into Q); band 2 -> bf16 [B,H,D,S] (V^T).
// ---------------------------------------------------------------------------
__global__ __launch_bounds__(256) void gemm_bt(const u16* __restrict__ A,
                                               const u16* __restrict__ B,
                                               void* __restrict__ dst,
                                               int K, int mode) {
  __shared__ __align__(16) u16 As[2][128 * 64];   // 32 KB
  __shared__ __align__(16) u16 Bs[2][128 * 64];   // 32 KB
  const int tid  = threadIdx.x;
  const int wave = tid >> 6, lane = tid & 63;
  const int quad = lane >> 4, m16 = lane & 15;
  const int wm = (wave >> 1) * 64, wn = (wave & 1) * 64;

  // XCD-aware swizzle: each XCD gets a contiguous logical tile range.
  const int nwg  = gridDim.x * gridDim.y;
  const int orig = blockIdx.y * gridDim.x + blockIdx.x;
  const int lid  = (orig & 7) * (nwg >> 3) + (orig >> 3);
  const size_t bi = (size_t)(lid / gridDim.x) * 128;
  const size_t bj = (size_t)(lid % gridDim.x) * 128;

  f32x4 acc[4][4];
  const f32x4 fz = {0.f, 0.f, 0.f, 0.f};
#pragma unroll
  for (int i = 0; i < 4; ++i)
#pragma unroll
    for (int j = 0; j < 4; ++j) acc[i][j] = fz;

  // staging descriptors: 4 chunks A + 4 chunks B per wave, fixed across K
  const u16* gA[4]; const u16* gB[4]; int lofs[4];
#pragma unroll
  for (int j = 0; j < 4; ++j) {
    const int t  = (wave * 4 + j) * 64 + lane;   // linear chunk id in tile
    const int r  = t >> 3;                       // tile row
    const int cs = t & 7;                        // stored (swizzled) chunk
    const int c  = cs ^ (r & 7);                 // global chunk
    gA[j] = A + (bi + r) * (size_t)K + c * 8;
    gB[j] = B + (bj + r) * (size_t)K + c * 8;
    lofs[j] = t * 8;
  }

  // prologue: stage K-tile 0 into buffer 0
#pragma unroll
  for (int j = 0; j < 4; ++j) GLOAD_LDS16(gA[j], &As[0][lofs[j]]);
#pragma unroll
  for (int j = 0; j < 4; ++j) GLOAD_LDS16(gB[j], &Bs[0][lofs[j]]);

  const int nIter = K >> 6;
  for (int it = 0; it < nIter; ++it) {
    DRAIN_VMEM();                         // cur-buf loads landed in LDS
    __syncthreads();                      // all waves done with other buf
    if (it + 1 < nIter) {
      const int ko = (it + 1) << 6;
      const int nb = (it + 1) & 1;
#pragma unroll
      for (int j = 0; j < 4; ++j) GLOAD_LDS16(gA[j] + ko, &As[nb][lofs[j]]);
#pragma unroll
      for (int j = 0; j < 4; ++j) GLOAD_LDS16(gB[j] + ko, &Bs[nb][lofs[j]]);
    }
    const int cb = it & 1;

    bf16x8 af[2][4], bfv[2][4];
#pragma unroll
    for (int kk = 0; kk < 2; ++kk) {
#pragma unroll
      for (int mt = 0; mt < 4; ++mt) {
        const int m = wm + mt * 16 + m16;
        af[kk][mt] = *(const bf16x8*)&As[cb][m * 64 + ((kk * 4 + quad) ^ (m & 7)) * 8];
      }
#pragma unroll
      for (int nt = 0; nt < 4; ++nt) {
        const int n = wn + nt * 16 + m16;
        bfv[kk][nt] = *(const bf16x8*)&Bs[cb][n * 64 + ((kk * 4 + quad) ^ (n & 7)) * 8];
      }
    }
#pragma unroll
    for (int kk = 0; kk < 2; ++kk)
#pragma unroll
      for (int mt = 0; mt < 4; ++mt)
#pragma unroll
        for (int nt = 0; nt < 4; ++nt)
          acc[mt][nt] = MFMA(af[kk][mt], bfv[kk][nt], acc[mt][nt]);
  }

  // ---------------- epilogue ----------------
  // C/D layout col=lane&15, row=quad*4+reg (m89/m91-verified)
  if (mode == 3 && (int)(bj >> 11) != 2) {
    // Fused-RoPE path for Q/K bands. Pair (dd, dd+64) lives at the SAME lane
    // of the adjacent wave (wave^1): wn toggles 0<->64, wm/rows identical.
    // Exchange via 32KB LDS scratch (reuse As; all As readers finished, the
    // first barrier orders the overwrite). Two mt-chunks of 32 floats/thread.
    float* xch = (float*)&As[0][0];                 // 8192 floats = 32 KB
    const int bandq = (int)(bj >> 11);              // 0=Q, 1=K
    const float qsc = (bandq == 0) ? 0.08838834764831845f : 1.0f;
#pragma unroll
    for (int ch = 0; ch < 2; ++ch) {
      __syncthreads();                              // As free for reuse
#pragma unroll
      for (int mh = 0; mh < 2; ++mh)
#pragma unroll
        for (int nt = 0; nt < 4; ++nt)
#pragma unroll
          for (int rg = 0; rg < 4; ++rg)
            xch[tid * 32 + mh * 16 + nt * 4 + rg] = acc[ch * 2 + mh][nt][rg];
      __syncthreads();
      const int ptid = tid ^ 64;                    // partner wave, same lane
#pragma unroll
      for (int mh = 0; mh < 2; ++mh) {
        const int mt = ch * 2 + mh;
#pragma unroll
        for (int nt = 0; nt < 4; ++nt) {
          const int col = (int)bj + wn + nt * 16 + m16;
          const int lc = col & 2047, hh = lc >> 7, dd = lc & 127;
          const float fr = __expf(-(float)(dd & 63) * (9.2103403719761836f / 64.0f));
#pragma unroll
          for (int rg = 0; rg < 4; ++rg) {
            const int row = (int)bi + wm + mt * 16 + quad * 4 + rg;
            const int bb = row >> 11, s = row & 2047;
            float sn, cs2;
            sincosf((float)s * fr, &sn, &cs2);
            const float v  = acc[mt][nt][rg];
            const float v2 = xch[ptid * 32 + mh * 16 + nt * 4 + rg];
            // wn==0 holds dd<64 (lo): lo' = lo*cos - hi*sin
            // wn==64 holds dd>=64 (hi): hi' = hi*cos + lo*sin
            const float o = (wn == 0) ? (v * cs2 - v2 * sn) : (v * cs2 + v2 * sn);
            const size_t idx = (size_t)bandq * 8388608u +
                ((((size_t)bb * 16 + hh) * 2048 + s) * 128 + dd);
            ((u16*)dst)[idx] = f2bf(o * qsc);
          }
        }
      }
    }
    return;   // uniform per block (mode, bj block-uniform)
  }

#pragma unroll
  for (int mt = 0; mt < 4; ++mt) {
#pragma unroll
    for (int nt = 0; nt < 4; ++nt) {
#pragma unroll
      for (int rg = 0; rg < 4; ++rg) {
        const int row = (int)bi + wm + mt * 16 + quad * 4 + rg;  // b*2048+s
        const int col = (int)bj + wn + nt * 16 + m16;
        const float v = acc[mt][nt][rg];
        if (mode == 2) {
          ((float*)dst)[(size_t)row * 2048 + col] = v;           // FP32 out
        } else {
          // mode 3 band 2 = V ([B,H,D,S])
          const int lc = col & 2047;
          const int bb = row >> 11, s = row & 2047, hh = lc >> 7, dd = lc & 127;
          const size_t idx = (size_t)2 * 8388608u +
              ((((size_t)bb * 16 + hh) * 128 + dd) * 2048 + s);
          ((u16*)dst)[idx] = f2bf(v);
        }
      }
    }
  }
}

// ---------------------------------------------------------------------------
// Flash v5 (byte-identical to round-4/12 passing runs): balanced qtile-pairs,
// 64 Q-rows/block, LDS 56 KB -> 2 blocks/CU, K dbuf + single-buffered V with
// counted mid-iter vmcnt(4).
// ---------------------------------------------------------------------------
__global__ __launch_bounds__(256, 2) void flash_attn(const u16* __restrict__ Q,
                                                     const u16* __restrict__ Kg,
                                                     const u16* __restrict__ Vg,
                                                     const float* __restrict__ mexp_g,
                                                     u16* __restrict__ ctx) {
  const int S = 2048, D = 128;
  __shared__ __align__(16) u16 Kt[2][64 * 128];   // [buf][key r][d], chunk swz
  __shared__ __align__(16) u16 Vt[128 * 64];      // [d][key], chunk swz, single buf
  __shared__ __align__(16) u16 Pt[64 * 64];       // [row][key], chunk swz
  const int tid  = threadIdx.x;
  const int wave = tid >> 6, lane = tid & 63;
  const int quad = lane >> 4, m16 = lane & 15;
  const int px = blockIdx.x >> 1;        // qtile pair index 0..7
  const int hl = blockIdx.x & 1;         // 64-row half within the qtile
  const int bh = blockIdx.y;
  const int b = bh >> 4, h = bh & 15;
  const size_t baseQK = (size_t)bh * S * D;
  const size_t baseV  = (size_t)bh * D * S;

  const u16* gK[4]; const u16* gV[4]; int lK[4], lV[4];
#pragma unroll
  for (int j = 0; j < 4; ++j) {
    const int t = (wave * 4 + j) * 64 + lane;    // linear 16B-chunk id
    {
      const int r = t >> 4, cs = t & 15;
      const int c = (cs & 8) | ((cs ^ r) & 7);   // global chunk (0..15)
      gK[j] = Kg + baseQK + (size_t)r * D + c * 8;   // + k0*D per tile
      lK[j] = t * 8;
    }
    {
      const int d = t >> 3, cs = t & 7;
      const int c = cs ^ (d & 7);                // global chunk (0..7)
      gV[j] = Vg + baseV + (size_t)d * S + c * 8;    // + k0 per tile
      lV[j] = t * 8;
    }
  }

  const f32x4 fz = {0.f, 0.f, 0.f, 0.f};

  for (int pass = 0; pass < 2; ++pass) {
    const int qtile = pass ? px : 15 - px;     // heavy first
    const int q0 = qtile * 128 + hl * 64;
    const int ktmax = 2 * qtile + hl;

    __syncthreads();

    bf16x8 qf[4];
#pragma unroll
    for (int kb = 0; kb < 4; ++kb)
      qf[kb] = *(const bf16x8*)&Q[baseQK +
          (size_t)(q0 + wave * 16 + m16) * D + kb * 32 + quad * 8];

    float li[4] = {0.f, 0.f, 0.f, 0.f};
    f32x4 oacc[8];
#pragma unroll
    for (int dt = 0; dt < 8; ++dt) oacc[dt] = fz;

#pragma unroll
    for (int j = 0; j < 4; ++j) GLOAD_LDS16(gK[j], &Kt[0][lK[j]]);

    for (int kt = 0; kt <= ktmax; ++kt) {
      const int k0 = kt * 64;
      const int cb = kt & 1;
      DRAIN_VMEM();
      __syncthreads();   // K(kt) resident; all waves done with Vt(kt-1), Kt[cb^1]

#pragma unroll
      for (int j = 0; j < 4; ++j) GLOAD_LDS16(gV[j] + k0, &Vt[lV[j]]);
      float madd[4];
#pragma unroll
      for (int nt = 0; nt < 4; ++nt)
        madd[nt] = mexp_g[b * S + k0 + nt * 16 + m16];
      if (kt < ktmax) {
#pragma unroll
        for (int j = 0; j < 4; ++j)
          GLOAD_LDS16(gK[j] + (size_t)(k0 + 64) * D, &Kt[cb ^ 1][lK[j]]);
      }

      f32x4 sacc[4];
#pragma unroll
      for (int nt = 0; nt < 4; ++nt) sacc[nt] = fz;
#pragma unroll
      for (int nt = 0; nt < 4; ++nt)
#pragma unroll
        for (int kb = 0; kb < 4; ++kb) {
          const int c = kb * 4 + quad;
          const int cs = (c & 8) | ((c ^ m16) & 7);
          bf16x8 kf = *(const bf16x8*)&Kt[cb][(nt * 16 + m16) * 128 + cs * 8];
          sacc[nt] = MFMA(qf[kb], kf, sacc[nt]);
        }

      if (kt < ktmax) { asm volatile("s_waitcnt vmcnt(4)" ::: "memory"); }
      else           { asm volatile("s_waitcnt vmcnt(0)" ::: "memory"); }
      __builtin_amdgcn_sched_barrier(0);

      const int R0   = q0 + wave * 16;
      const int prow = wave * 16 + quad * 4;
      if (k0 + 63 > R0) {
#pragma unroll
        for (int rg = 0; rg < 4; ++rg) {
          const int row = R0 + quad * 4 + rg;
          const int pr  = prow + rg;
          float ps = 0.f;
#pragma unroll
          for (int nt = 0; nt < 4; ++nt) {
            const int col = k0 + nt * 16 + m16;
            const float p = (col > row) ? 0.f : __expf(sacc[nt][rg] + madd[nt]);
            ps += p;
            const int c = nt * 2 + (m16 >> 3);
            Pt[pr * 64 + ((c ^ pr) & 7) * 8 + (m16 & 7)] = f2bf(p);
          }
          li[rg] += ps;
        }
      } else {
#pragma unroll
        for (int rg = 0; rg < 4; ++rg) {
          const int pr = prow + rg;
          float ps = 0.f;
#pragma unroll
          for (int nt = 0; nt < 4; ++nt) {
            const float p = __expf(sacc[nt][rg] + madd[nt]);
            ps += p;
            const int c = nt * 2 + (m16 >> 3);
            Pt[pr * 64 + ((c ^ pr) & 7) * 8 + (m16 & 7)] = f2bf(p);
          }
          li[rg] += ps;
        }
      }
      FENCE_LDS();

#pragma unroll
      for (int kb = 0; kb < 2; ++kb) {
        const int c = kb * 4 + quad;
        const int cs = (c ^ m16) & 7;
        bf16x8 pf = *(const bf16x8*)&Pt[(wave * 16 + m16) * 64 + cs * 8];
#pragma unroll
        for (int dt = 0; dt < 8; ++dt) {
          bf16x8 vf = *(const bf16x8*)&Vt[(dt * 16 + m16) * 64 + cs * 8];
          oacc[dt] = MFMA(pf, vf, oacc[dt]);
        }
      }
    }

#pragma unroll
    for (int rg = 0; rg < 4; ++rg) {
      float ls = li[rg];
#pragma unroll
      for (int mk = 1; mk < 16; mk <<= 1) ls += __shfl_xor(ls, mk, 64);
      const float inv = 1.0f / ls;
      const int srow = q0 + wave * 16 + quad * 4 + rg;
#pragma unroll
      for (int dt = 0; dt < 8; ++dt) {
        const int e = h * 128 + dt * 16 + m16;
        ctx[((size_t)b * S + srow) * 2048 + e] = f2bf(oacc[dt][rg] * inv);
      }
    }
  }
}

// ---------------------------------------------------------------------------
extern "C" void kernel_launch(void* const* d_in, const int* in_sizes, int n_in,
                              void* d_out, int out_size, void* d_ws, size_t ws_size,
                              hipStream_t stream) {
  (void)in_sizes; (void)n_in; (void)out_size; (void)ws_size;
  const int Bz = 2, S = 2048, E = 2048, H = 16;
  const size_t NX = (size_t)Bz * S * E;   // 8388608
  const size_t NW = (size_t)E * E;        // 4194304

  // ws layout (~117.5 MB)
  char* ws = (char*)d_ws;
  int*   flags = (int*)ws;                 // 6 ints
  float* mexp  = (float*)(ws + 256);       // 16 KB
  u16* xc  = (u16*)(ws + 256 + 16384);
  u16* Wqc = xc + NX;                      // Wq,Wk,Wv contiguous = fused B
  u16* Qr  = Wqc + 4 * NW;                 // [B,H,S,D]; Qr,Kr,Vt contiguous
  u16* Kr  = Qr + NX;                      // [B,H,S,D]
  u16* Vt  = Kr + NX;                      // [B,H,D,S]
  u16* ctx = Vt + NX;                      // [B,S,E]
  u16* Woc = Wqc + 3 * NW;
  (void)Kr; (void)Vt;

  probe_all<<<6, 256, 0, stream>>>((const u16*)d_in[0], (const u16*)d_in[1],
                                   (const u16*)d_in[2], (const u16*)d_in[3],
                                   (const u16*)d_in[4], (const u16*)d_in[5], flags);

  prep_all<<<12304, 256, 0, stream>>>(d_in[0], d_in[2], d_in[3], d_in[4],
                                      d_in[5], d_in[1], xc, mexp, flags);

  // fused QKV projection (+fused RoPE on Q/K bands): C[4096,6144] = xc @ Wqkv^T
  gemm_bt<<<dim3(48, 32), 256, 0, stream>>>(xc, Wqc, Qr, E, 3);
  flash_attn<<<dim3(16, Bz * H), 256, 0, stream>>>(Qr, Qr + NX, Qr + 2 * NX, mexp, ctx);
  gemm_bt<<<dim3(16, 32), 256, 0, stream>>>(ctx, Woc, d_out, E, 2);
}

// Round 16
// 407.128 us; speedup vs baseline: 2.4367x; 2.4367x over previous
//
#include <hip/hip_runtime.h>
#include <math.h>

typedef unsigned short u16;
typedef __attribute__((ext_vector_type(8))) short bf16x8;     // 8 bf16 = 4 VGPRs (MFMA A/B frag)
typedef __attribute__((ext_vector_type(8))) unsigned short u16x8;
typedef __attribute__((ext_vector_type(4))) float f32x4;      // MFMA C/D frag

#define MFMA(a, b, c) __builtin_amdgcn_mfma_f32_16x16x32_bf16((a), (b), (c), 0, 0, 0)

// async global->LDS, 16B per lane; LDS dest = wave-uniform base + lane*16,
// global source = per-lane VGPR address (gather OK)
#define GLOAD_LDS16(g, l)                                                     \
  __builtin_amdgcn_global_load_lds(                                           \
      (const __attribute__((address_space(1))) void*)(g),                     \
      (__attribute__((address_space(3))) void*)(l), 16, 0, 0)

// DRAIN_VMEM: all in-flight global_load_lds landed in LDS (explicit, before barrier)
#define DRAIN_VMEM() asm volatile("s_waitcnt vmcnt(0)" ::: "memory")
// FENCE_LDS: order same-wave ds_write -> ds_read handoff (Pt) explicitly.
#define FENCE_LDS()                                                            \
  do {                                                                         \
    asm volatile("s_waitcnt lgkmcnt(0)" ::: "memory");                         \
    __builtin_amdgcn_sched_barrier(0);                                         \
  } while (0)

__device__ __forceinline__ float bf2f(u16 u) {
  union { unsigned int i; float f; } x; x.i = ((unsigned int)u) << 16; return x.f;
}
__device__ __forceinline__ u16 f2bf(float f) {
  union { float f; unsigned int i; } x; x.f = f;
  unsigned int r = x.i + 0x7FFFu + ((x.i >> 16) & 1u);   // round-to-nearest-even
  return (u16)(r >> 16);
}

// ---------------------------------------------------------------------------
// Dtype probes, one launch: flag[i]=1 bf16, 0 fp32.
// ---------------------------------------------------------------------------
__global__ __launch_bounds__(256) void probe_all(const u16* p0, const u16* p1,
                                                 const u16* p2, const u16* p3,
                                                 const u16* p4, const u16* p5,
                                                 int* __restrict__ flags) {
  const u16* ps[6] = {p0, p1, p2, p3, p4, p5};
  const u16* p = ps[blockIdx.x];
  __shared__ int cnt;
  if (threadIdx.x == 0) cnt = 0;
  __syncthreads();
  const u16 u = p[threadIdx.x * 2];
  const int e = (u >> 7) & 0xFF;
  atomicAdd(&cnt, (e >= 110 && e <= 135) ? 1 : 0);
  __syncthreads();
  if (threadIdx.x == 0) flags[blockIdx.x] = (cnt > 128) ? 1 : 0;
}

// ---------------------------------------------------------------------------
// prep_all: merged bf16 canonicalization of x + 4 weights, mexp build, and
// RoPE cos/sin table build (sincosf lives HERE, in a trivial kernel — never
// in the GEMM epilogue where it spilled the register file to scratch).
// blocks [0,12288): converts. [12288,12304): mexp. [12304,12816): rope table
// rtab[s*64+j] = {cos(s*f_j), sin(s*f_j)}, 2048x64 float2 = 1 MB.
// ---------------------------------------------------------------------------
__global__ __launch_bounds__(256) void prep_all(const void* __restrict__ x_in,
                                                const void* __restrict__ wq_in,
                                                const void* __restrict__ wk_in,
                                                const void* __restrict__ wv_in,
                                                const void* __restrict__ wo_in,
                                                const void* __restrict__ mask_in,
                                                u16* __restrict__ xc,
                                                float* __restrict__ mexp,
                                                float2* __restrict__ rtab,
                                                const int* __restrict__ flags) {
  const int blk = blockIdx.x;
  if (blk < 12288) {
    const int i = blk * 256 + threadIdx.x;
    const void* in; u16* out; int fi, off;
    if (i < (1 << 20)) {                 // x: NX/8 = 2^20 vec8 elems
      in = x_in; out = xc; fi = 0; off = i;
    } else {
      const int k = i - (1 << 20);
      const int seg = k >> 19;           // each W: NW/8 = 2^19 vec8 elems
      off = k & ((1 << 19) - 1);
      in = (seg == 0) ? wq_in : (seg == 1) ? wk_in : (seg == 2) ? wv_in : wo_in;
      out = xc + ((size_t)1 << 23) + ((size_t)seg << 22);  // Wqc..Woc contiguous
      fi = 2 + seg;
    }
    if (flags[fi]) {
      ((u16x8*)out)[off] = ((const u16x8*)in)[off];
    } else {
      const float* f = (const float*)in + (size_t)off * 8;
      u16x8 r;
#pragma unroll
      for (int j = 0; j < 8; ++j) r[j] = f2bf(f[j]);
      ((u16x8*)out)[off] = r;
    }
  } else if (blk < 12304) {
    const int i = (blk - 12288) * 256 + threadIdx.x;   // 0..4095
    const float m = flags[1] ? bf2f(((const u16*)mask_in)[i]) : ((const float*)mask_in)[i];
    mexp[i] = (1.0f - m) * -1e9f;
  } else {
    const int idx = (blk - 12304) * 256 + threadIdx.x; // 0..131071
    const int s = idx >> 6, j = idx & 63;
    const float f = __expf(-(float)j * (9.2103403719761836f / 64.0f));
    float sn, cs;
    sincosf((float)s * f, &sn, &cs);
    rtab[idx] = make_float2(cs, sn);
  }
}

// ---------------------------------------------------------------------------
// GEMM (round-12 proven structure, NO XCD swizzle): C[M,N] = A[M,K]@B[N,K]^T.
// 128x128 tile, BK=64, double-buffered global_load_lds, single barrier/K-iter,
// XOR-swizzled unpadded LDS (chunk c of row r at c^(r&7)).
// mode 2: fp32 out [M,2048]
// mode 3: QKV fused N=6144; bands 0/1 (Q/K) -> bf16 [B,H,S,D] with FUSED ROPE
//   (pairing verified on HW in r14: pair (dd,dd+64) = same lane of wave^1;
//    exchange via XOR-keyed LDS scratch, cos/sin from precomputed table);
//   band 2 (V) -> bf16 [B,H,D,S].
// ---------------------------------------------------------------------------
__global__ __launch_bounds__(256) void gemm_bt(const u16* __restrict__ A,
                                               const u16* __restrict__ B,
                                               void* __restrict__ dst,
                                               const float2* __restrict__ rtab,
                                               int K, int mode) {
  __shared__ __align__(16) u16 As[2][128 * 64];   // 32 KB
  __shared__ __align__(16) u16 Bs[2][128 * 64];   // 32 KB
  const int tid  = threadIdx.x;
  const int wave = tid >> 6, lane = tid & 63;
  const int quad = lane >> 4, m16 = lane & 15;
  const int wm = (wave >> 1) * 64, wn = (wave & 1) * 64;
  const size_t bi = (size_t)blockIdx.y * 128;
  const size_t bj = (size_t)blockIdx.x * 128;

  f32x4 acc[4][4];
  const f32x4 fz = {0.f, 0.f, 0.f, 0.f};
#pragma unroll
  for (int i = 0; i < 4; ++i)
#pragma unroll
    for (int j = 0; j < 4; ++j) acc[i][j] = fz;

  // staging descriptors: 4 chunks A + 4 chunks B per wave, fixed across K
  const u16* gA[4]; const u16* gB[4]; int lofs[4];
#pragma unroll
  for (int j = 0; j < 4; ++j) {
    const int t  = (wave * 4 + j) * 64 + lane;   // linear chunk id in tile
    const int r  = t >> 3;                       // tile row
    const int cs = t & 7;                        // stored (swizzled) chunk
    const int c  = cs ^ (r & 7);                 // global chunk
    gA[j] = A + (bi + r) * (size_t)K + c * 8;
    gB[j] = B + (bj + r) * (size_t)K + c * 8;
    lofs[j] = t * 8;
  }

  // prologue: stage K-tile 0 into buffer 0
#pragma unroll
  for (int j = 0; j < 4; ++j) GLOAD_LDS16(gA[j], &As[0][lofs[j]]);
#pragma unroll
  for (int j = 0; j < 4; ++j) GLOAD_LDS16(gB[j], &Bs[0][lofs[j]]);

  const int nIter = K >> 6;
  for (int it = 0; it < nIter; ++it) {
    DRAIN_VMEM();                         // cur-buf loads landed in LDS
    __syncthreads();                      // all waves done with other buf
    if (it + 1 < nIter) {
      const int ko = (it + 1) << 6;
      const int nb = (it + 1) & 1;
#pragma unroll
      for (int j = 0; j < 4; ++j) GLOAD_LDS16(gA[j] + ko, &As[nb][lofs[j]]);
#pragma unroll
      for (int j = 0; j < 4; ++j) GLOAD_LDS16(gB[j] + ko, &Bs[nb][lofs[j]]);
    }
    const int cb = it & 1;

    bf16x8 af[2][4], bfv[2][4];
#pragma unroll
    for (int kk = 0; kk < 2; ++kk) {
#pragma unroll
      for (int mt = 0; mt < 4; ++mt) {
        const int m = wm + mt * 16 + m16;
        af[kk][mt] = *(const bf16x8*)&As[cb][m * 64 + ((kk * 4 + quad) ^ (m & 7)) * 8];
      }
#pragma unroll
      for (int nt = 0; nt < 4; ++nt) {
        const int n = wn + nt * 16 + m16;
        bfv[kk][nt] = *(const bf16x8*)&Bs[cb][n * 64 + ((kk * 4 + quad) ^ (n & 7)) * 8];
      }
    }
#pragma unroll
    for (int kk = 0; kk < 2; ++kk)
#pragma unroll
      for (int mt = 0; mt < 4; ++mt)
#pragma unroll
        for (int nt = 0; nt < 4; ++nt)
          acc[mt][nt] = MFMA(af[kk][mt], bfv[kk][nt], acc[mt][nt]);
  }

  // ---------------- epilogue ----------------
  // C/D layout col=lane&15, row=quad*4+reg (m89/m91-verified)
  if (mode == 3 && (int)(bj >> 11) != 2) {
    // Fused RoPE for Q/K bands. Pair (dd, dd+64) = SAME lane of wave^1.
    // Exchange via LDS scratch (reuse As; barrier orders the overwrite).
    // Element index XOR'd with lane&31 -> 2 lanes/bank (conflict-free, m136).
    // cos/sin from rtab (L2-hot 1MB table) -> NO libm call, NO scratch spill.
    float* xch = (float*)&As[0][0];                 // 8192 floats = 32 KB
    const int bandq = (int)(bj >> 11);              // 0=Q, 1=K
    const float qsc = (bandq == 0) ? 0.08838834764831845f : 1.0f;
    const int key = lane & 31;
#pragma unroll
    for (int ch = 0; ch < 2; ++ch) {
      __syncthreads();                              // As free for reuse
#pragma unroll
      for (int mh = 0; mh < 2; ++mh)
#pragma unroll
        for (int nt = 0; nt < 4; ++nt)
#pragma unroll
          for (int rg = 0; rg < 4; ++rg)
            xch[tid * 32 + ((mh * 16 + nt * 4 + rg) ^ key)] = acc[ch * 2 + mh][nt][rg];
      __syncthreads();
      const int ptid = tid ^ 64;                    // partner wave, same lane
#pragma unroll
      for (int mh = 0; mh < 2; ++mh) {
        const int mt = ch * 2 + mh;
#pragma unroll
        for (int nt = 0; nt < 4; ++nt) {
          const int col = (int)bj + wn + nt * 16 + m16;
          const int lc = col & 2047, hh = lc >> 7, dd = lc & 127;
#pragma unroll
          for (int rg = 0; rg < 4; ++rg) {
            const int row = (int)bi + wm + mt * 16 + quad * 4 + rg;
            const int bb = row >> 11, s = row & 2047;
            const float2 t = rtab[s * 64 + (dd & 63)];
            const float v  = acc[mt][nt][rg];
            const float v2 = xch[ptid * 32 + ((mh * 16 + nt * 4 + rg) ^ key)];
            // wn==0 holds dd<64 (lo): lo' = lo*cos - hi*sin
            // wn==64 holds dd>=64 (hi): hi' = hi*cos + lo*sin
            const float o = (wn == 0) ? (v * t.x - v2 * t.y) : (v * t.x + v2 * t.y);
            const size_t idx = (size_t)bandq * 8388608u +
                ((((size_t)bb * 16 + hh) * 2048 + s) * 128 + dd);
            ((u16*)dst)[idx] = f2bf(o * qsc);
          }
        }
      }
    }
    return;   // uniform per block (mode, bj block-uniform)
  }

#pragma unroll
  for (int mt = 0; mt < 4; ++mt) {
#pragma unroll
    for (int nt = 0; nt < 4; ++nt) {
#pragma unroll
      for (int rg = 0; rg < 4; ++rg) {
        const int row = (int)bi + wm + mt * 16 + quad * 4 + rg;  // b*2048+s
        const int col = (int)bj + wn + nt * 16 + m16;
        const float v = acc[mt][nt][rg];
        if (mode == 2) {
          ((float*)dst)[(size_t)row * 2048 + col] = v;           // FP32 out
        } else {
          // mode 3 band 2 = V ([B,H,D,S])
          const int lc = col & 2047;
          const int bb = row >> 11, s = row & 2047, hh = lc >> 7, dd = lc & 127;
          const size_t idx = (size_t)2 * 8388608u +
              ((((size_t)bb * 16 + hh) * 128 + dd) * 2048 + s);
          ((u16*)dst)[idx] = f2bf(v);
        }
      }
    }
  }
}

// ---------------------------------------------------------------------------
// Flash v5 (byte-identical to round-4/12 passing runs): balanced qtile-pairs,
// 64 Q-rows/block, LDS 56 KB -> 2 blocks/CU, K dbuf + single-buffered V with
// counted mid-iter vmcnt(4).
// ---------------------------------------------------------------------------
__global__ __launch_bounds__(256, 2) void flash_attn(const u16* __restrict__ Q,
                                                     const u16* __restrict__ Kg,
                                                     const u16* __restrict__ Vg,
                                                     const float* __restrict__ mexp_g,
                                                     u16* __restrict__ ctx) {
  const int S = 2048, D = 128;
  __shared__ __align__(16) u16 Kt[2][64 * 128];   // [buf][key r][d], chunk swz
  __shared__ __align__(16) u16 Vt[128 * 64];      // [d][key], chunk swz, single buf
  __shared__ __align__(16) u16 Pt[64 * 64];       // [row][key], chunk swz
  const int tid  = threadIdx.x;
  const int wave = tid >> 6, lane = tid & 63;
  const int quad = lane >> 4, m16 = lane & 15;
  const int px = blockIdx.x >> 1;        // qtile pair index 0..7
  const int hl = blockIdx.x & 1;         // 64-row half within the qtile
  const int bh = blockIdx.y;
  const int b = bh >> 4, h = bh & 15;
  const size_t baseQK = (size_t)bh * S * D;
  const size_t baseV  = (size_t)bh * D * S;

  const u16* gK[4]; const u16* gV[4]; int lK[4], lV[4];
#pragma unroll
  for (int j = 0; j < 4; ++j) {
    const int t = (wave * 4 + j) * 64 + lane;    // linear 16B-chunk id
    {
      const int r = t >> 4, cs = t & 15;
      const int c = (cs & 8) | ((cs ^ r) & 7);   // global chunk (0..15)
      gK[j] = Kg + baseQK + (size_t)r * D + c * 8;   // + k0*D per tile
      lK[j] = t * 8;
    }
    {
      const int d = t >> 3, cs = t & 7;
      const int c = cs ^ (d & 7);                // global chunk (0..7)
      gV[j] = Vg + baseV + (size_t)d * S + c * 8;    // + k0 per tile
      lV[j] = t * 8;
    }
  }

  const f32x4 fz = {0.f, 0.f, 0.f, 0.f};

  for (int pass = 0; pass < 2; ++pass) {
    const int qtile = pass ? px : 15 - px;     // heavy first
    const int q0 = qtile * 128 + hl * 64;
    const int ktmax = 2 * qtile + hl;

    __syncthreads();

    bf16x8 qf[4];
#pragma unroll
    for (int kb = 0; kb < 4; ++kb)
      qf[kb] = *(const bf16x8*)&Q[baseQK +
          (size_t)(q0 + wave * 16 + m16) * D + kb * 32 + quad * 8];

    float li[4] = {0.f, 0.f, 0.f, 0.f};
    f32x4 oacc[8];
#pragma unroll
    for (int dt = 0; dt < 8; ++dt) oacc[dt] = fz;

#pragma unroll
    for (int j = 0; j < 4; ++j) GLOAD_LDS16(gK[j], &Kt[0][lK[j]]);

    for (int kt = 0; kt <= ktmax; ++kt) {
      const int k0 = kt * 64;
      const int cb = kt & 1;
      DRAIN_VMEM();
      __syncthreads();   // K(kt) resident; all waves done with Vt(kt-1), Kt[cb^1]

#pragma unroll
      for (int j = 0; j < 4; ++j) GLOAD_LDS16(gV[j] + k0, &Vt[lV[j]]);
      float madd[4];
#pragma unroll
      for (int nt = 0; nt < 4; ++nt)
        madd[nt] = mexp_g[b * S + k0 + nt * 16 + m16];
      if (kt < ktmax) {
#pragma unroll
        for (int j = 0; j < 4; ++j)
          GLOAD_LDS16(gK[j] + (size_t)(k0 + 64) * D, &Kt[cb ^ 1][lK[j]]);
      }

      f32x4 sacc[4];
#pragma unroll
      for (int nt = 0; nt < 4; ++nt) sacc[nt] = fz;
#pragma unroll
      for (int nt = 0; nt < 4; ++nt)
#pragma unroll
        for (int kb = 0; kb < 4; ++kb) {
          const int c = kb * 4 + quad;
          const int cs = (c & 8) | ((c ^ m16) & 7);
          bf16x8 kf = *(const bf16x8*)&Kt[cb][(nt * 16 + m16) * 128 + cs * 8];
          sacc[nt] = MFMA(qf[kb], kf, sacc[nt]);
        }

      if (kt < ktmax) { asm volatile("s_waitcnt vmcnt(4)" ::: "memory"); }
      else           { asm volatile("s_waitcnt vmcnt(0)" ::: "memory"); }
      __builtin_amdgcn_sched_barrier(0);

      const int R0   = q0 + wave * 16;
      const int prow = wave * 16 + quad * 4;
      if (k0 + 63 > R0) {
#pragma unroll
        for (int rg = 0; rg < 4; ++rg) {
          const int row = R0 + quad * 4 + rg;
          const int pr  = prow + rg;
          float ps = 0.f;
#pragma unroll
          for (int nt = 0; nt < 4; ++nt) {
            const int col = k0 + nt * 16 + m16;
            const float p = (col > row) ? 0.f : __expf(sacc[nt][rg] + madd[nt]);
            ps += p;
            const int c = nt * 2 + (m16 >> 3);
            Pt[pr * 64 + ((c ^ pr) & 7) * 8 + (m16 & 7)] = f2bf(p);
          }
          li[rg] += ps;
        }
      } else {
#pragma unroll
        for (int rg = 0; rg < 4; ++rg) {
          const int pr = prow + rg;
          float ps = 0.f;
#pragma unroll
          for (int nt = 0; nt < 4; ++nt) {
            const float p = __expf(sacc[nt][rg] + madd[nt]);
            ps += p;
            const int c = nt * 2 + (m16 >> 3);
            Pt[pr * 64 + ((c ^ pr) & 7) * 8 + (m16 & 7)] = f2bf(p);
          }
          li[rg] += ps;
        }
      }
      FENCE_LDS();

#pragma unroll
      for (int kb = 0; kb < 2; ++kb) {
        const int c = kb * 4 + quad;
        const int cs = (c ^ m16) & 7;
        bf16x8 pf = *(const bf16x8*)&Pt[(wave * 16 + m16) * 64 + cs * 8];
#pragma unroll
        for (int dt = 0; dt < 8; ++dt) {
          bf16x8 vf = *(const bf16x8*)&Vt[(dt * 16 + m16) * 64 + cs * 8];
          oacc[dt] = MFMA(pf, vf, oacc[dt]);
        }
      }
    }

#pragma unroll
    for (int rg = 0; rg < 4; ++rg) {
      float ls = li[rg];
#pragma unroll
      for (int mk = 1; mk < 16; mk <<= 1) ls += __shfl_xor(ls, mk, 64);
      const float inv = 1.0f / ls;
      const int srow = q0 + wave * 16 + quad * 4 + rg;
#pragma unroll
      for (int dt = 0; dt < 8; ++dt) {
        const int e = h * 128 + dt * 16 + m16;
        ctx[((size_t)b * S + srow) * 2048 + e] = f2bf(oacc[dt][rg] * inv);
      }
    }
  }
}

// ---------------------------------------------------------------------------
extern "C" void kernel_launch(void* const* d_in, const int* in_sizes, int n_in,
                              void* d_out, int out_size, void* d_ws, size_t ws_size,
                              hipStream_t stream) {
  (void)in_sizes; (void)n_in; (void)out_size; (void)ws_size;
  const int Bz = 2, S = 2048, E = 2048, H = 16;
  const size_t NX = (size_t)Bz * S * E;   // 8388608
  const size_t NW = (size_t)E * E;        // 4194304

  // ws layout (~117.5 MB)
  char* ws = (char*)d_ws;
  int*   flags = (int*)ws;                 // 6 ints
  float* mexp  = (float*)(ws + 256);       // 16 KB
  u16* xc  = (u16*)(ws + 256 + 16384);
  u16* Wqc = xc + NX;                      // Wq,Wk,Wv contiguous = fused B
  u16* Qr  = Wqc + 4 * NW;                 // [B,H,S,D]; Qr,Kr,Vt contiguous
  u16* Kr  = Qr + NX;                      // [B,H,S,D]
  u16* Vt  = Kr + NX;                      // [B,H,D,S]
  u16* ctx = Vt + NX;                      // [B,S,E]
  u16* Woc = Wqc + 3 * NW;
  // RoPE cos/sin table lives in the (not-yet-used) ctx buffer: 1 MB of 16.8 MB.
  // Lifetime: written by prep_all, read by QKV gemm, then flash overwrites ctx.
  float2* rtab = (float2*)ctx;
  (void)Kr; (void)Vt;

  probe_all<<<6, 256, 0, stream>>>((const u16*)d_in[0], (const u16*)d_in[1],
                                   (const u16*)d_in[2], (const u16*)d_in[3],
                                   (const u16*)d_in[4], (const u16*)d_in[5], flags);

  prep_all<<<12816, 256, 0, stream>>>(d_in[0], d_in[2], d_in[3], d_in[4],
                                      d_in[5], d_in[1], xc, mexp, rtab, flags);

  // fused QKV projection (+fused RoPE on Q/K bands): C[4096,6144] = xc @ Wqkv^T
  gemm_bt<<<dim3(48, 32), 256, 0, stream>>>(xc, Wqc, Qr, rtab, E, 3);
  flash_attn<<<dim3(16, Bz * H), 256, 0, stream>>>(Qr, Qr + NX, Qr + 2 * NX, mexp, ctx);
  gemm_bt<<<dim3(16, 32), 256, 0, stream>>>(ctx, Woc, d_out, rtab, E, 2);
}

// Round 18
// 403.520 us; speedup vs baseline: 2.4585x; 1.0089x over previous
//
#include <hip/hip_runtime.h>
#include <math.h>

typedef unsigned short u16;
typedef __attribute__((ext_vector_type(8))) short bf16x8;     // 8 bf16 = 4 VGPRs (MFMA A/B frag)
typedef __attribute__((ext_vector_type(8))) unsigned short u16x8;
typedef __attribute__((ext_vector_type(4))) float f32x4;      // MFMA C/D frag

#define MFMA(a, b, c) __builtin_amdgcn_mfma_f32_16x16x32_bf16((a), (b), (c), 0, 0, 0)

// async global->LDS, 16B per lane; LDS dest = wave-uniform base + lane*16,
// global source = per-lane VGPR address (gather OK)
#define GLOAD_LDS16(g, l)                                                     \
  __builtin_amdgcn_global_load_lds(                                           \
      (const __attribute__((address_space(1))) void*)(g),                     \
      (__attribute__((address_space(3))) void*)(l), 16, 0, 0)

// DRAIN_VMEM: all in-flight global_load_lds landed in LDS (explicit, before barrier)
#define DRAIN_VMEM() asm volatile("s_waitcnt vmcnt(0)" ::: "memory")
// FENCE_LDS: order same-wave ds_write -> ds_read handoff (Pt) explicitly.
#define FENCE_LDS()                                                            \
  do {                                                                         \
    asm volatile("s_waitcnt lgkmcnt(0)" ::: "memory");                         \
    __builtin_amdgcn_sched_barrier(0);                                         \
  } while (0)

__device__ __forceinline__ float bf2f(u16 u) {
  union { unsigned int i; float f; } x; x.i = ((unsigned int)u) << 16; return x.f;
}
__device__ __forceinline__ u16 f2bf(float f) {
  union { float f; unsigned int i; } x; x.f = f;
  unsigned int r = x.i + 0x7FFFu + ((x.i >> 16) & 1u);   // round-to-nearest-even
  return (u16)(r >> 16);
}

// ---------------------------------------------------------------------------
// Dtype probes, one launch: flag[i]=1 bf16, 0 fp32.
// ---------------------------------------------------------------------------
__global__ __launch_bounds__(256) void probe_all(const u16* p0, const u16* p1,
                                                 const u16* p2, const u16* p3,
                                                 const u16* p4, const u16* p5,
                                                 int* __restrict__ flags) {
  const u16* ps[6] = {p0, p1, p2, p3, p4, p5};
  const u16* p = ps[blockIdx.x];
  __shared__ int cnt;
  if (threadIdx.x == 0) cnt = 0;
  __syncthreads();
  const u16 u = p[threadIdx.x * 2];
  const int e = (u >> 7) & 0xFF;
  atomicAdd(&cnt, (e >= 110 && e <= 135) ? 1 : 0);
  __syncthreads();
  if (threadIdx.x == 0) flags[blockIdx.x] = (cnt > 128) ? 1 : 0;
}

// ---------------------------------------------------------------------------
// prep_all: merged bf16 canonicalization of x + 4 weights, mexp build, and
// RoPE cos/sin table build (sincosf lives HERE, never in the GEMM epilogue).
// blocks [0,12288): converts. [12288,12304): mexp. [12304,12816): rope table
// rtab[s*64+j] = {cos(s*f_j), sin(s*f_j)}, 2048x64 float2 = 1 MB.
// ---------------------------------------------------------------------------
__global__ __launch_bounds__(256) void prep_all(const void* __restrict__ x_in,
                                                const void* __restrict__ wq_in,
                                                const void* __restrict__ wk_in,
                                                const void* __restrict__ wv_in,
                                                const void* __restrict__ wo_in,
                                                const void* __restrict__ mask_in,
                                                u16* __restrict__ xc,
                                                float* __restrict__ mexp,
                                                float2* __restrict__ rtab,
                                                const int* __restrict__ flags) {
  const int blk = blockIdx.x;
  if (blk < 12288) {
    const int i = blk * 256 + threadIdx.x;
    const void* in; u16* out; int fi, off;
    if (i < (1 << 20)) {                 // x: NX/8 = 2^20 vec8 elems
      in = x_in; out = xc; fi = 0; off = i;
    } else {
      const int k = i - (1 << 20);
      const int seg = k >> 19;           // each W: NW/8 = 2^19 vec8 elems
      off = k & ((1 << 19) - 1);
      in = (seg == 0) ? wq_in : (seg == 1) ? wk_in : (seg == 2) ? wv_in : wo_in;
      out = xc + ((size_t)1 << 23) + ((size_t)seg << 22);  // Wqc..Woc contiguous
      fi = 2 + seg;
    }
    if (flags[fi]) {
      ((u16x8*)out)[off] = ((const u16x8*)in)[off];
    } else {
      const float* f = (const float*)in + (size_t)off * 8;
      u16x8 r;
#pragma unroll
      for (int j = 0; j < 8; ++j) r[j] = f2bf(f[j]);
      ((u16x8*)out)[off] = r;
    }
  } else if (blk < 12304) {
    const int i = (blk - 12288) * 256 + threadIdx.x;   // 0..4095
    const float m = flags[1] ? bf2f(((const u16*)mask_in)[i]) : ((const float*)mask_in)[i];
    mexp[i] = (1.0f - m) * -1e9f;
  } else {
    const int idx = (blk - 12304) * 256 + threadIdx.x; // 0..131071
    const int s = idx >> 6, j = idx & 63;
    const float f = __expf(-(float)j * (9.2103403719761836f / 64.0f));
    float sn, cs;
    sincosf((float)s * f, &sn, &cs);
    rtab[idx] = make_float2(cs, sn);
  }
}

// ---------------------------------------------------------------------------
// GEMM (r16-verified structure + XCD-aware block swizzle, isolated retest):
// C[M,N] = A[M,K]@B[N,K]^T. 128x128 tile, BK=64, dbuf global_load_lds,
// single barrier/K-iter, XOR-swizzled unpadded LDS (chunk c of row r at
// c^(r&7)). Swizzle: lid = (orig&7)*(nwg/8) + orig>>3 — bijective (nwg%8==0).
// mode 2: fp32 out [M,2048]
// mode 3: QKV fused N=6144; bands 0/1 (Q/K) -> bf16 [B,H,S,D] with FUSED ROPE
//   (r16-verified: pair (dd,dd+64) = same lane of wave^1; XOR-keyed LDS
//    exchange, cos/sin from table); band 2 (V) -> bf16 [B,H,D,S].
// ---------------------------------------------------------------------------
__global__ __launch_bounds__(256) void gemm_bt(const u16* __restrict__ A,
                                               const u16* __restrict__ B,
                                               void* __restrict__ dst,
                                               const float2* __restrict__ rtab,
                                               int K, int mode) {
  __shared__ __align__(16) u16 As[2][128 * 64];   // 32 KB
  __shared__ __align__(16) u16 Bs[2][128 * 64];   // 32 KB
  const int tid  = threadIdx.x;
  const int wave = tid >> 6, lane = tid & 63;
  const int quad = lane >> 4, m16 = lane & 15;
  const int wm = (wave >> 1) * 64, wn = (wave & 1) * 64;

  // XCD-aware swizzle: each XCD gets a contiguous logical tile range (T1).
  const int nwg  = gridDim.x * gridDim.y;
  const int orig = blockIdx.y * gridDim.x + blockIdx.x;
  const int lid  = (orig & 7) * (nwg >> 3) + (orig >> 3);
  const size_t bi = (size_t)(lid / gridDim.x) * 128;
  const size_t bj = (size_t)(lid % gridDim.x) * 128;

  f32x4 acc[4][4];
  const f32x4 fz = {0.f, 0.f, 0.f, 0.f};
#pragma unroll
  for (int i = 0; i < 4; ++i)
#pragma unroll
    for (int j = 0; j < 4; ++j) acc[i][j] = fz;

  // staging descriptors: 4 chunks A + 4 chunks B per wave, fixed across K
  const u16* gA[4]; const u16* gB[4]; int lofs[4];
#pragma unroll
  for (int j = 0; j < 4; ++j) {
    const int t  = (wave * 4 + j) * 64 + lane;   // linear chunk id in tile
    const int r  = t >> 3;                       // tile row
    const int cs = t & 7;                        // stored (swizzled) chunk
    const int c  = cs ^ (r & 7);                 // global chunk
    gA[j] = A + (bi + r) * (size_t)K + c * 8;
    gB[j] = B + (bj + r) * (size_t)K + c * 8;
    lofs[j] = t * 8;
  }

  // prologue: stage K-tile 0 into buffer 0
#pragma unroll
  for (int j = 0; j < 4; ++j) GLOAD_LDS16(gA[j], &As[0][lofs[j]]);
#pragma unroll
  for (int j = 0; j < 4; ++j) GLOAD_LDS16(gB[j], &Bs[0][lofs[j]]);

  const int nIter = K >> 6;
  for (int it = 0; it < nIter; ++it) {
    DRAIN_VMEM();                         // cur-buf loads landed in LDS
    __syncthreads();                      // all waves done with other buf
    if (it + 1 < nIter) {
      const int ko = (it + 1) << 6;
      const int nb = (it + 1) & 1;
#pragma unroll
      for (int j = 0; j < 4; ++j) GLOAD_LDS16(gA[j] + ko, &As[nb][lofs[j]]);
#pragma unroll
      for (int j = 0; j < 4; ++j) GLOAD_LDS16(gB[j] + ko, &Bs[nb][lofs[j]]);
    }
    const int cb = it & 1;

    bf16x8 af[2][4], bfv[2][4];
#pragma unroll
    for (int kk = 0; kk < 2; ++kk) {
#pragma unroll
      for (int mt = 0; mt < 4; ++mt) {
        const int m = wm + mt * 16 + m16;
        af[kk][mt] = *(const bf16x8*)&As[cb][m * 64 + ((kk * 4 + quad) ^ (m & 7)) * 8];
      }
#pragma unroll
      for (int nt = 0; nt < 4; ++nt) {
        const int n = wn + nt * 16 + m16;
        bfv[kk][nt] = *(const bf16x8*)&Bs[cb][n * 64 + ((kk * 4 + quad) ^ (n & 7)) * 8];
      }
    }
#pragma unroll
    for (int kk = 0; kk < 2; ++kk)
#pragma unroll
      for (int mt = 0; mt < 4; ++mt)
#pragma unroll
        for (int nt = 0; nt < 4; ++nt)
          acc[mt][nt] = MFMA(af[kk][mt], bfv[kk][nt], acc[mt][nt]);
  }

  // ---------------- epilogue ----------------
  // C/D layout col=lane&15, row=quad*4+reg (m89/m91-verified)
  if (mode == 3 && (int)(bj >> 11) != 2) {
    // Fused RoPE for Q/K bands (r16-verified). Pair = same lane of wave^1.
    float* xch = (float*)&As[0][0];                 // 8192 floats = 32 KB
    const int bandq = (int)(bj >> 11);              // 0=Q, 1=K
    const float qsc = (bandq == 0) ? 0.08838834764831845f : 1.0f;
    const int key = lane & 31;
#pragma unroll
    for (int ch = 0; ch < 2; ++ch) {
      __syncthreads();                              // As free for reuse
#pragma unroll
      for (int mh = 0; mh < 2; ++mh)
#pragma unroll
        for (int nt = 0; nt < 4; ++nt)
#pragma unroll
          for (int rg = 0; rg < 4; ++rg)
            xch[tid * 32 + ((mh * 16 + nt * 4 + rg) ^ key)] = acc[ch * 2 + mh][nt][rg];
      __syncthreads();
      const int ptid = tid ^ 64;                    // partner wave, same lane
#pragma unroll
      for (int mh = 0; mh < 2; ++mh) {
        const int mt = ch * 2 + mh;
#pragma unroll
        for (int nt = 0; nt < 4; ++nt) {
          const int col = (int)bj + wn + nt * 16 + m16;
          const int lc = col & 2047, hh = lc >> 7, dd = lc & 127;
#pragma unroll
          for (int rg = 0; rg < 4; ++rg) {
            const int row = (int)bi + wm + mt * 16 + quad * 4 + rg;
            const int bb = row >> 11, s = row & 2047;
            const float2 t = rtab[s * 64 + (dd & 63)];
            const float v  = acc[mt][nt][rg];
            const float v2 = xch[ptid * 32 + ((mh * 16 + nt * 4 + rg) ^ key)];
            // wn==0 holds dd<64 (lo): lo' = lo*cos - hi*sin
            // wn==64 holds dd>=64 (hi): hi' = hi*cos + lo*sin
            const float o = (wn == 0) ? (v * t.x - v2 * t.y) : (v * t.x + v2 * t.y);
            const size_t idx = (size_t)bandq * 8388608u +
                ((((size_t)bb * 16 + hh) * 2048 + s) * 128 + dd);
            ((u16*)dst)[idx] = f2bf(o * qsc);
          }
        }
      }
    }
    return;   // uniform per block (mode, bj block-uniform)
  }

#pragma unroll
  for (int mt = 0; mt < 4; ++mt) {
#pragma unroll
    for (int nt = 0; nt < 4; ++nt) {
#pragma unroll
      for (int rg = 0; rg < 4; ++rg) {
        const int row = (int)bi + wm + mt * 16 + quad * 4 + rg;  // b*2048+s
        const int col = (int)bj + wn + nt * 16 + m16;
        const float v = acc[mt][nt][rg];
        if (mode == 2) {
          ((float*)dst)[(size_t)row * 2048 + col] = v;           // FP32 out
        } else {
          // mode 3 band 2 = V ([B,H,D,S])
          const int lc = col & 2047;
          const int bb = row >> 11, s = row & 2047, hh = lc >> 7, dd = lc & 127;
          const size_t idx = (size_t)2 * 8388608u +
              ((((size_t)bb * 16 + hh) * 128 + dd) * 2048 + s);
          ((u16*)dst)[idx] = f2bf(v);
        }
      }
    }
  }
}

// ---------------------------------------------------------------------------
// Flash v5 + T5 setprio around MFMA clusters (2 independent blocks/CU at
// different phases = m191's positive regime, not m190's barrier-locked null).
// Otherwise byte-identical to round-4/12/16 passing runs.
// ---------------------------------------------------------------------------
__global__ __launch_bounds__(256, 2) void flash_attn(const u16* __restrict__ Q,
                                                     const u16* __restrict__ Kg,
                                                     const u16* __restrict__ Vg,
                                                     const float* __restrict__ mexp_g,
                                                     u16* __restrict__ ctx) {
  const int S = 2048, D = 128;
  __shared__ __align__(16) u16 Kt[2][64 * 128];   // [buf][key r][d], chunk swz
  __shared__ __align__(16) u16 Vt[128 * 64];      // [d][key], chunk swz, single buf
  __shared__ __align__(16) u16 Pt[64 * 64];       // [row][key], chunk swz
  const int tid  = threadIdx.x;
  const int wave = tid >> 6, lane = tid & 63;
  const int quad = lane >> 4, m16 = lane & 15;
  const int px = blockIdx.x >> 1;        // qtile pair index 0..7
  const int hl = blockIdx.x & 1;         // 64-row half within the qtile
  const int bh = blockIdx.y;
  const int b = bh >> 4, h = bh & 15;
  const size_t baseQK = (size_t)bh * S * D;
  const size_t baseV  = (size_t)bh * D * S;

  const u16* gK[4]; const u16* gV[4]; int lK[4], lV[4];
#pragma unroll
  for (int j = 0; j < 4; ++j) {
    const int t = (wave * 4 + j) * 64 + lane;    // linear 16B-chunk id
    {
      const int r = t >> 4, cs = t & 15;
      const int c = (cs & 8) | ((cs ^ r) & 7);   // global chunk (0..15)
      gK[j] = Kg + baseQK + (size_t)r * D + c * 8;   // + k0*D per tile
      lK[j] = t * 8;
    }
    {
      const int d = t >> 3, cs = t & 7;
      const int c = cs ^ (d & 7);                // global chunk (0..7)
      gV[j] = Vg + baseV + (size_t)d * S + c * 8;    // + k0 per tile
      lV[j] = t * 8;
    }
  }

  const f32x4 fz = {0.f, 0.f, 0.f, 0.f};

  for (int pass = 0; pass < 2; ++pass) {
    const int qtile = pass ? px : 15 - px;     // heavy first
    const int q0 = qtile * 128 + hl * 64;
    const int ktmax = 2 * qtile + hl;

    __syncthreads();

    bf16x8 qf[4];
#pragma unroll
    for (int kb = 0; kb < 4; ++kb)
      qf[kb] = *(const bf16x8*)&Q[baseQK +
          (size_t)(q0 + wave * 16 + m16) * D + kb * 32 + quad * 8];

    float li[4] = {0.f, 0.f, 0.f, 0.f};
    f32x4 oacc[8];
#pragma unroll
    for (int dt = 0; dt < 8; ++dt) oacc[dt] = fz;

#pragma unroll
    for (int j = 0; j < 4; ++j) GLOAD_LDS16(gK[j], &Kt[0][lK[j]]);

    for (int kt = 0; kt <= ktmax; ++kt) {
      const int k0 = kt * 64;
      const int cb = kt & 1;
      DRAIN_VMEM();
      __syncthreads();   // K(kt) resident; all waves done with Vt(kt-1), Kt[cb^1]

#pragma unroll
      for (int j = 0; j < 4; ++j) GLOAD_LDS16(gV[j] + k0, &Vt[lV[j]]);
      float madd[4];
#pragma unroll
      for (int nt = 0; nt < 4; ++nt)
        madd[nt] = mexp_g[b * S + k0 + nt * 16 + m16];
      if (kt < ktmax) {
#pragma unroll
        for (int j = 0; j < 4; ++j)
          GLOAD_LDS16(gK[j] + (size_t)(k0 + 64) * D, &Kt[cb ^ 1][lK[j]]);
      }

      f32x4 sacc[4];
#pragma unroll
      for (int nt = 0; nt < 4; ++nt) sacc[nt] = fz;
      __builtin_amdgcn_s_setprio(1);
#pragma unroll
      for (int nt = 0; nt < 4; ++nt)
#pragma unroll
        for (int kb = 0; kb < 4; ++kb) {
          const int c = kb * 4 + quad;
          const int cs = (c & 8) | ((c ^ m16) & 7);
          bf16x8 kf = *(const bf16x8*)&Kt[cb][(nt * 16 + m16) * 128 + cs * 8];
          sacc[nt] = MFMA(qf[kb], kf, sacc[nt]);
        }
      __builtin_amdgcn_s_setprio(0);

      if (kt < ktmax) { asm volatile("s_waitcnt vmcnt(4)" ::: "memory"); }
      else           { asm volatile("s_waitcnt vmcnt(0)" ::: "memory"); }
      __builtin_amdgcn_sched_barrier(0);

      const int R0   = q0 + wave * 16;
      const int prow = wave * 16 + quad * 4;
      if (k0 + 63 > R0) {
#pragma unroll
        for (int rg = 0; rg < 4; ++rg) {
          const int row = R0 + quad * 4 + rg;
          const int pr  = prow + rg;
          float ps = 0.f;
#pragma unroll
          for (int nt = 0; nt < 4; ++nt) {
            const int col = k0 + nt * 16 + m16;
            const float p = (col > row) ? 0.f : __expf(sacc[nt][rg] + madd[nt]);
            ps += p;
            const int c = nt * 2 + (m16 >> 3);
            Pt[pr * 64 + ((c ^ pr) & 7) * 8 + (m16 & 7)] = f2bf(p);
          }
          li[rg] += ps;
        }
      } else {
#pragma unroll
        for (int rg = 0; rg < 4; ++rg) {
          const int pr = prow + rg;
          float ps = 0.f;
#pragma unroll
          for (int nt = 0; nt < 4; ++nt) {
            const float p = __expf(sacc[nt][rg] + madd[nt]);
            ps += p;
            const int c = nt * 2 + (m16 >> 3);
            Pt[pr * 64 + ((c ^ pr) & 7) * 8 + (m16 & 7)] = f2bf(p);
          }
          li[rg] += ps;
        }
      }
      FENCE_LDS();

      __builtin_amdgcn_s_setprio(1);
#pragma unroll
      for (int kb = 0; kb < 2; ++kb) {
        const int c = kb * 4 + quad;
        const int cs = (c ^ m16) & 7;
        bf16x8 pf = *(const bf16x8*)&Pt[(wave * 16 + m16) * 64 + cs * 8];
#pragma unroll
        for (int dt = 0; dt < 8; ++dt) {
          bf16x8 vf = *(const bf16x8*)&Vt[(dt * 16 + m16) * 64 + cs * 8];
          oacc[dt] = MFMA(pf, vf, oacc[dt]);
        }
      }
      __builtin_amdgcn_s_setprio(0);
    }

#pragma unroll
    for (int rg = 0; rg < 4; ++rg) {
      float ls = li[rg];
#pragma unroll
      for (int mk = 1; mk < 16; mk <<= 1) ls += __shfl_xor(ls, mk, 64);
      const float inv = 1.0f / ls;
      const int srow = q0 + wave * 16 + quad * 4 + rg;
#pragma unroll
      for (int dt = 0; dt < 8; ++dt) {
        const int e = h * 128 + dt * 16 + m16;
        ctx[((size_t)b * S + srow) * 2048 + e] = f2bf(oacc[dt][rg] * inv);
      }
    }
  }
}

// ---------------------------------------------------------------------------
extern "C" void kernel_launch(void* const* d_in, const int* in_sizes, int n_in,
                              void* d_out, int out_size, void* d_ws, size_t ws_size,
                              hipStream_t stream) {
  (void)in_sizes; (void)n_in; (void)out_size; (void)ws_size;
  const int Bz = 2, S = 2048, E = 2048, H = 16;
  const size_t NX = (size_t)Bz * S * E;   // 8388608
  const size_t NW = (size_t)E * E;        // 4194304

  // ws layout (~117.5 MB)
  char* ws = (char*)d_ws;
  int*   flags = (int*)ws;                 // 6 ints
  float* mexp  = (float*)(ws + 256);       // 16 KB
  u16* xc  = (u16*)(ws + 256 + 16384);
  u16* Wqc = xc + NX;                      // Wq,Wk,Wv contiguous = fused B
  u16* Qr  = Wqc + 4 * NW;                 // [B,H,S,D]; Qr,Kr,Vt contiguous
  u16* ctx = Qr + 3 * NX;                  // [B,S,E]
  u16* Woc = Wqc + 3 * NW;
  // RoPE cos/sin table lives in the (not-yet-used) ctx buffer: 1 MB of 16.8 MB.
  // Lifetime: written by prep_all, read by QKV gemm, then flash overwrites ctx.
  float2* rtab = (float2*)ctx;

  probe_all<<<6, 256, 0, stream>>>((const u16*)d_in[0], (const u16*)d_in[1],
                                   (const u16*)d_in[2], (const u16*)d_in[3],
                                   (const u16*)d_in[4], (const u16*)d_in[5], flags);

  prep_all<<<12816, 256, 0, stream>>>(d_in[0], d_in[2], d_in[3], d_in[4],
                                      d_in[5], d_in[1], xc, mexp, rtab, flags);

  // fused QKV projection (+fused RoPE on Q/K bands): C[4096,6144] = xc @ Wqkv^T
  gemm_bt<<<dim3(48, 32), 256, 0, stream>>>(xc, Wqc, Qr, rtab, E, 3);
  flash_attn<<<dim3(16, Bz * H), 256, 0, stream>>>(Qr, Qr + NX, Qr + 2 * NX, mexp, ctx);
  gemm_bt<<<dim3(16, 32), 256, 0, stream>>>(ctx, Woc, d_out, rtab, E, 2);
}